// Round 5
// baseline (649.385 us; speedup 1.0000x reference)
//
#include <hip/hip_runtime.h>
#include <cstddef>

// Shapes: B=128, T=256, H=128, 4H=512, D=2E=128, GENOME=1e6, OUT*T=256
// d_out: out[128][256] (32768 f32) then emb[128][256][128] (4194304 f32)
// ws (floats): xg @0 (16777216) | hs @16777216 (4194304) | wf_hi @20971520 (32768)
//              | wf_lo @21004288 (32768) | partials @21037056 (1048576)

typedef __attribute__((ext_vector_type(8))) _Float16 f16x8;
typedef __attribute__((ext_vector_type(4))) float f32x4;

__device__ __forceinline__ float frcp(float x) { return __builtin_amdgcn_rcpf(x); }
__device__ __forceinline__ float sigm(float x) { return frcp(1.0f + __expf(-x)); }
__device__ __forceinline__ float ftanh(float x) {
  float e = __expf(2.0f * x);
  return (e - 1.0f) * frcp(e + 1.0f);
}
// split x into fp16 hi + fp16 lo (lo pre-scaled by 2^11); returns bit patterns
__device__ __forceinline__ void split2(float x, unsigned short& hi, unsigned short& lo) {
  _Float16 h = (_Float16)x;
  _Float16 l = (_Float16)((x - (float)h) * 2048.0f);
  hi = *(unsigned short*)&h;
  lo = *(unsigned short*)&l;
}
// LDS-only barrier: does NOT drain vmcnt (keeps global prefetch/stores in flight)
__device__ __forceinline__ void barrier_lds() {
  asm volatile("s_waitcnt lgkmcnt(0)\n\ts_barrier" ::: "memory");
}

// select component jj (0..3) of an f32x4 with compile-time indices (no scratch)
#define SEL4(v, jj) ((jj) == 0 ? (v)[0] : (jj) == 1 ? (v)[1] : (jj) == 2 ? (v)[2] : (v)[3])

// ---------- embedding gather ----------
__global__ void k_embed(const int* __restrict__ idx, const float4* __restrict__ table4,
                        float4* __restrict__ emb4) {
  int i = blockIdx.x * blockDim.x + threadIdx.x;   // B*T*2*16 = 1,048,576
  int p = i >> 4, j = i & 15;
  int id = idx[p];
  emb4[(size_t)p * 16 + j] = table4[(size_t)id * 16 + j];
}

// ---------- generic C[M,N] = A[M,K] @ B[N,K]^T, 64x64 tile ----------
__global__ __launch_bounds__(256) void k_gemm_tn(
    const float* __restrict__ A, const float* __restrict__ Bm, float* __restrict__ C,
    int K, int kchunks, int N, size_t partstride)
{
  __shared__ float As[64][65];
  __shared__ float Bs[64][68];
  const int tid = threadIdx.x;
  const int tx = tid & 15, ty = tid >> 4;
  const int m0 = blockIdx.x * 64, n0 = blockIdx.y * 64;
  float acc[4][4] = {};
  size_t kbase = (size_t)blockIdx.z * kchunks * 64;
  for (int kc = 0; kc < kchunks; ++kc) {
    size_t k0 = kbase + (size_t)kc * 64;
    #pragma unroll
    for (int it = 0; it < 4; ++it) {
      int fi = it * 256 + tid;
      int row = fi >> 4, col4 = fi & 15;
      float4 va = *(const float4*)(A + (size_t)(m0 + row) * K + k0 + col4 * 4);
      As[row][col4*4+0] = va.x; As[row][col4*4+1] = va.y;
      As[row][col4*4+2] = va.z; As[row][col4*4+3] = va.w;
      float4 vb = *(const float4*)(Bm + (size_t)(n0 + row) * K + k0 + col4 * 4);
      Bs[col4*4+0][row] = vb.x; Bs[col4*4+1][row] = vb.y;
      Bs[col4*4+2][row] = vb.z; Bs[col4*4+3][row] = vb.w;
    }
    __syncthreads();
    #pragma unroll 8
    for (int k = 0; k < 64; ++k) {
      float a0 = As[ty*4+0][k], a1 = As[ty*4+1][k], a2 = As[ty*4+2][k], a3 = As[ty*4+3][k];
      float b0 = Bs[k][tx*4+0], b1 = Bs[k][tx*4+1], b2 = Bs[k][tx*4+2], b3 = Bs[k][tx*4+3];
      acc[0][0] += a0*b0; acc[0][1] += a0*b1; acc[0][2] += a0*b2; acc[0][3] += a0*b3;
      acc[1][0] += a1*b0; acc[1][1] += a1*b1; acc[1][2] += a1*b2; acc[1][3] += a1*b3;
      acc[2][0] += a2*b0; acc[2][1] += a2*b1; acc[2][2] += a2*b2; acc[2][3] += a2*b3;
      acc[3][0] += a3*b0; acc[3][1] += a3*b1; acc[3][2] += a3*b2; acc[3][3] += a3*b3;
    }
    __syncthreads();
  }
  float* Cp = C + (size_t)blockIdx.z * partstride;
  #pragma unroll
  for (int i = 0; i < 4; ++i) {
    float4 v = make_float4(acc[i][0], acc[i][1], acc[i][2], acc[i][3]);
    *(float4*)(Cp + (size_t)(m0 + ty*4 + i) * N + n0 + tx*4) = v;
  }
}

// ---------- xg := LN(xg)*g_ih + (b_ih + b_hh), in place, one wave per row ----------
__global__ __launch_bounds__(256) void k_xln(float4* __restrict__ xg4,
                                             const float4* __restrict__ g4,
                                             const float4* __restrict__ bi4,
                                             const float4* __restrict__ bh4) {
  int row = blockIdx.x * 4 + (threadIdx.x >> 6);   // 32768 rows
  int lane = threadIdx.x & 63;
  float4* r = xg4 + (size_t)row * 128;
  float4 a = r[lane], b = r[lane + 64];
  float s = a.x + a.y + a.z + a.w + b.x + b.y + b.z + b.w;
  float q = a.x*a.x + a.y*a.y + a.z*a.z + a.w*a.w + b.x*b.x + b.y*b.y + b.z*b.z + b.w*b.w;
  #pragma unroll
  for (int off = 32; off; off >>= 1) { s += __shfl_xor(s, off); q += __shfl_xor(q, off); }
  float m = s * (1.0f / 512.0f);
  float rs = rsqrtf(q * (1.0f / 512.0f) - m * m + 1e-5f);
  float4 ga = g4[lane], gb = g4[64 + lane];
  float4 ia = bi4[lane], ib = bi4[64 + lane];
  float4 ha = bh4[lane], hb = bh4[64 + lane];
  a.x = (a.x - m) * rs * ga.x + ia.x + ha.x; a.y = (a.y - m) * rs * ga.y + ia.y + ha.y;
  a.z = (a.z - m) * rs * ga.z + ia.z + ha.z; a.w = (a.w - m) * rs * ga.w + ia.w + ha.w;
  b.x = (b.x - m) * rs * gb.x + ib.x + hb.x; b.y = (b.y - m) * rs * gb.y + ib.y + hb.y;
  b.z = (b.z - m) * rs * gb.z + ib.z + hb.z; b.w = (b.w - m) * rs * gb.w + ib.w + hb.w;
  r[lane] = a; r[lane + 64] = b;
}

// ---------- W_hh -> dual fp16 A-fragments (hi + scaled lo), k = kc*32+8*(l>>4)+i ----------
__global__ void k_wprep(const float* __restrict__ Whh, uint4* __restrict__ wfh,
                        uint4* __restrict__ wfl) {
  int i = blockIdx.x * 256 + threadIdx.x;  // 8192 = 32*4*64
  int l = i & 63, kc = (i >> 6) & 3, mt = i >> 8;
  int row = mt * 16 + (l & 15);
  int kb = kc * 32 + 8 * (l >> 4);
  float4 a = *(const float4*)(Whh + row * 128 + kb);
  float4 c = *(const float4*)(Whh + row * 128 + kb + 4);
  unsigned short h0,h1,h2,h3,h4,h5,h6,h7, l0,l1,l2,l3,l4,l5,l6,l7;
  split2(a.x,h0,l0); split2(a.y,h1,l1); split2(a.z,h2,l2); split2(a.w,h3,l3);
  split2(c.x,h4,l4); split2(c.y,h5,l5); split2(c.z,h6,l6); split2(c.w,h7,l7);
  uint4 oh, ol;
  oh.x = h0 | ((unsigned)h1 << 16); oh.y = h2 | ((unsigned)h3 << 16);
  oh.z = h4 | ((unsigned)h5 << 16); oh.w = h6 | ((unsigned)h7 << 16);
  ol.x = l0 | ((unsigned)l1 << 16); ol.y = l2 | ((unsigned)l3 << 16);
  ol.z = l4 | ((unsigned)l5 << 16); ol.w = l6 | ((unsigned)l7 << 16);
  wfh[i] = oh; wfl[i] = ol;
}

// ---------- MFMA LSTM scan: dual-fp16 (effective fp32) W,h; one block per batch row ----------
__global__ __launch_bounds__(512, 2) void k_scan(
    const float* __restrict__ xln,   // [B][T][512]  (LN(x)*g_ih + b_ih + b_hh)
    const uint4* __restrict__ wfh,   // [32][4][64] A-frags f16 hi
    const uint4* __restrict__ wfl,   // [32][4][64] A-frags f16 lo (x2048)
    const float* __restrict__ h0, const float* __restrict__ c0,
    const float* __restrict__ g_hh,
    const float* __restrict__ g_c,  const float* __restrict__ b_c,
    float* __restrict__ hs)          // [B][T][128]
{
  const int b = blockIdx.x;
  const int tid = threadIdx.x;
  const int w = tid >> 6, l = tid & 63;
  const int lg = l >> 4;                 // fragment row-group 0..3
  const int jj = (l & 15) >> 2;          // which of the 4 acc components this lane owns
  const bool wr = (l & 3) == 0;          // one writer per hidden unit
  const int u = w * 16 + lg * 4 + jj;    // hidden unit owned by this lane (0..127)
  const float inv2048 = 1.0f / 2048.0f;

  __shared__ alignas(16) unsigned short hbh[128];  // h hi, fp16, k-contiguous
  __shared__ alignas(16) unsigned short hbl[128];  // h lo (x2048), fp16
  __shared__ float2 hred[8];
  __shared__ float2 cred[8];

  // A-frags resident: tiles {w, 8+w, 16+w, 24+w} = i,f,g,o gate rows [16w,16w+16)
  uint4 afh0[4], afh1[4], afh2[4], afh3[4];
  uint4 afl0[4], afl1[4], afl2[4], afl3[4];
  #pragma unroll
  for (int kc = 0; kc < 4; ++kc) {
    afh0[kc] = wfh[((w     ) * 4 + kc) * 64 + l];
    afh1[kc] = wfh[((w +  8) * 4 + kc) * 64 + l];
    afh2[kc] = wfh[((w + 16) * 4 + kc) * 64 + l];
    afh3[kc] = wfh[((w + 24) * 4 + kc) * 64 + l];
    afl0[kc] = wfl[((w     ) * 4 + kc) * 64 + l];
    afl1[kc] = wfl[((w +  8) * 4 + kc) * 64 + l];
    afl2[kc] = wfl[((w + 16) * 4 + kc) * 64 + l];
    afl3[kc] = wfl[((w + 24) * 4 + kc) * 64 + l];
  }
  #pragma unroll
  for (int kc = 0; kc < 4; ++kc) {
    asm volatile("" : "+v"(afh0[kc].x), "+v"(afh0[kc].y), "+v"(afh0[kc].z), "+v"(afh0[kc].w));
    asm volatile("" : "+v"(afh1[kc].x), "+v"(afh1[kc].y), "+v"(afh1[kc].z), "+v"(afh1[kc].w));
    asm volatile("" : "+v"(afh2[kc].x), "+v"(afh2[kc].y), "+v"(afh2[kc].z), "+v"(afh2[kc].w));
    asm volatile("" : "+v"(afh3[kc].x), "+v"(afh3[kc].y), "+v"(afh3[kc].z), "+v"(afh3[kc].w));
    asm volatile("" : "+v"(afl0[kc].x), "+v"(afl0[kc].y), "+v"(afl0[kc].z), "+v"(afl0[kc].w));
    asm volatile("" : "+v"(afl1[kc].x), "+v"(afl1[kc].y), "+v"(afl1[kc].z), "+v"(afl1[kc].w));
    asm volatile("" : "+v"(afl2[kc].x), "+v"(afl2[kc].y), "+v"(afl2[kc].z), "+v"(afl2[kc].w));
    asm volatile("" : "+v"(afl3[kc].x), "+v"(afl3[kc].y), "+v"(afl3[kc].z), "+v"(afl3[kc].w));
  }

  const float ghI = g_hh[u], ghF = g_hh[128 + u], ghG = g_hh[256 + u], ghO = g_hh[384 + u];
  const float gcv = g_c[u], bcv = b_c[u];
  float cv = c0[b * 128 + u];
  if (wr) {
    unsigned short hi, lo;
    split2(h0[b * 128 + u], hi, lo);
    hbh[u] = hi; hbl[u] = lo;
  }
  __syncthreads();

  const float* xgb = xln + (size_t)b * 256 * 512;
  float* hsb = hs + (size_t)b * 256 * 128;

  // prefetch x for t=0
  float xI = xgb[u], xF = xgb[128 + u], xG = xgb[256 + u], xO = xgb[384 + u];

  for (int t = 0; t < 256; ++t) {
    // issue next step's x loads now; consumed next iteration (full step to cover latency)
    const float* xn = xgb + (((t + 1) & 255) << 9);
    float nI = xn[u], nF = xn[128 + u], nG = xn[256 + u], nO = xn[384 + u];

    // matvec via MFMA: B-frag = h broadcast over all 16 cols, same k-map as A.
    // acc = Whi*hhi + 2^-11 * (Whi*hlo' + Wlo'*hhi)   (lo' pre-scaled by 2^11)
    f32x4 acc0 = {0,0,0,0}, acc1 = {0,0,0,0}, acc2 = {0,0,0,0}, acc3 = {0,0,0,0};
    f32x4 e0 = {0,0,0,0}, e1 = {0,0,0,0}, e2 = {0,0,0,0}, e3 = {0,0,0,0};
    #pragma unroll
    for (int kc = 0; kc < 4; ++kc) {
      uint4 buh = *(const uint4*)((const char*)hbh + kc * 64 + 16 * lg);
      uint4 bul = *(const uint4*)((const char*)hbl + kc * 64 + 16 * lg);
      f16x8 bh = *(f16x8*)&buh;
      f16x8 bl = *(f16x8*)&bul;
      acc0 = __builtin_amdgcn_mfma_f32_16x16x32_f16(*(f16x8*)&afh0[kc], bh, acc0, 0, 0, 0);
      acc1 = __builtin_amdgcn_mfma_f32_16x16x32_f16(*(f16x8*)&afh1[kc], bh, acc1, 0, 0, 0);
      acc2 = __builtin_amdgcn_mfma_f32_16x16x32_f16(*(f16x8*)&afh2[kc], bh, acc2, 0, 0, 0);
      acc3 = __builtin_amdgcn_mfma_f32_16x16x32_f16(*(f16x8*)&afh3[kc], bh, acc3, 0, 0, 0);
      e0 = __builtin_amdgcn_mfma_f32_16x16x32_f16(*(f16x8*)&afh0[kc], bl, e0, 0, 0, 0);
      e1 = __builtin_amdgcn_mfma_f32_16x16x32_f16(*(f16x8*)&afh1[kc], bl, e1, 0, 0, 0);
      e2 = __builtin_amdgcn_mfma_f32_16x16x32_f16(*(f16x8*)&afh2[kc], bl, e2, 0, 0, 0);
      e3 = __builtin_amdgcn_mfma_f32_16x16x32_f16(*(f16x8*)&afh3[kc], bl, e3, 0, 0, 0);
      e0 = __builtin_amdgcn_mfma_f32_16x16x32_f16(*(f16x8*)&afl0[kc], bh, e0, 0, 0, 0);
      e1 = __builtin_amdgcn_mfma_f32_16x16x32_f16(*(f16x8*)&afl1[kc], bh, e1, 0, 0, 0);
      e2 = __builtin_amdgcn_mfma_f32_16x16x32_f16(*(f16x8*)&afl2[kc], bh, e2, 0, 0, 0);
      e3 = __builtin_amdgcn_mfma_f32_16x16x32_f16(*(f16x8*)&afl3[kc], bh, e3, 0, 0, 0);
    }
    f32x4 a0, a1, a2, a3;
    #pragma unroll
    for (int j = 0; j < 4; ++j) {
      a0[j] = acc0[j] + e0[j] * inv2048;
      a1[j] = acc1[j] + e1[j] * inv2048;
      a2[j] = acc2[j] + e2[j] * inv2048;
      a3[j] = acc3[j] + e3[j] * inv2048;
    }

    // LN-h stats over the 512 matvec outputs (deterministic: per-wave slot + fixed-order sum)
    float s = 0.f, q = 0.f;
    #pragma unroll
    for (int j = 0; j < 4; ++j) {
      s += a0[j] + a1[j] + a2[j] + a3[j];
      q += a0[j]*a0[j] + a1[j]*a1[j] + a2[j]*a2[j] + a3[j]*a3[j];
    }
    s += __shfl_xor(s, 16); s += __shfl_xor(s, 32);
    q += __shfl_xor(q, 16); q += __shfl_xor(q, 32);
    if (l == 0) hred[w] = make_float2(s, q);

    barrier_lds();                         // barrier 1: hred ready, hb consumed

    float rsx = 0.f, rsq = 0.f;
    #pragma unroll
    for (int i = 0; i < 8; ++i) { float2 v = hred[i]; rsx += v.x; rsq += v.y; }
    float mh = rsx * (1.0f / 512.0f);
    float rh = rsqrtf(rsq * (1.0f / 512.0f) - mh * mh + 1e-5f);

    // this lane's hidden unit u: gates (b_hh already folded into xln)
    float aI = SEL4(a0, jj), aF = SEL4(a1, jj), aG = SEL4(a2, jj), aO = SEL4(a3, jj);
    float gI = xI + (aI - mh) * rh * ghI;
    float gF = xF + (aF - mh) * rh * ghF;
    float gG = xG + (aG - mh) * rh * ghG;
    float gO = xO + (aO - mh) * rh * ghO;

    float cn = sigm(gF) * cv + sigm(gI) * ftanh(gG);
    cv = cn;

    // c-stats: full-wave reduce (4x replica per unit, bit-identical, folded by /512)
    float cs = cn, cq = cn * cn;
    #pragma unroll
    for (int off = 32; off; off >>= 1) { cs += __shfl_xor(cs, off); cq += __shfl_xor(cq, off); }
    if (l == 0) cred[w] = make_float2(cs, cq);

    barrier_lds();                         // barrier 2: cred ready

    float tcs = 0.f, tcq = 0.f;
    #pragma unroll
    for (int i = 0; i < 8; ++i) { float2 v = cred[i]; tcs += v.x; tcq += v.y; }
    float mc = tcs * (1.0f / 512.0f);      // 4x replication / 128 units
    float rc = rsqrtf(tcq * (1.0f / 512.0f) - mc * mc + 1e-5f);

    float lnc = (cn - mc) * rc * gcv + bcv;
    float hn = sigm(gO) * ftanh(lnc);

    if (wr) {
      unsigned short hi, lo;
      split2(hn, hi, lo);
      hbh[u] = hi; hbl[u] = lo;
      hsb[(size_t)t * 128 + u] = hn;       // fire-and-forget (no vmcnt drain at barriers)
    }
    xI = nI; xF = nF; xG = nG; xO = nO;

    barrier_lds();                         // barrier 3: hb visible for next step
  }
}

// ---------- k-split reduce + bias + sigmoid ----------
__global__ void k_reduce(const float* __restrict__ part, const float* __restrict__ b_out,
                         float* __restrict__ out) {
  int i = blockIdx.x * 256 + threadIdx.x;   // 0..32767 = b*256+o
  float s = b_out[i & 255];
  #pragma unroll
  for (int z = 0; z < 32; ++z) s += part[(size_t)z * 32768 + i];
  out[i] = sigm(s);
}

extern "C" void kernel_launch(void* const* d_in, const int* in_sizes, int n_in,
                              void* d_out, int out_size, void* d_ws, size_t ws_size,
                              hipStream_t stream) {
  const int*   idx   = (const int*)  d_in[0];
  const float* h0    = (const float*)d_in[1];
  const float* c0    = (const float*)d_in[2];
  const float* table = (const float*)d_in[3];
  const float* W_ih  = (const float*)d_in[4];
  const float* W_hh  = (const float*)d_in[5];
  const float* g_ih  = (const float*)d_in[6];
  const float* b_ih  = (const float*)d_in[7];
  const float* g_hh  = (const float*)d_in[8];
  const float* b_hh  = (const float*)d_in[9];
  const float* g_c   = (const float*)d_in[10];
  const float* b_c   = (const float*)d_in[11];
  const float* W_out = (const float*)d_in[12];
  const float* b_out = (const float*)d_in[13];

  float* out  = (float*)d_out;             // 32768
  float* emb  = out + 32768;               // 4194304 (output #2)
  float* ws   = (float*)d_ws;
  float* xg   = ws;                        // 16777216 floats (becomes xln in place)
  float* hsb  = ws + 16777216;             // 4194304
  uint4* wfh  = (uint4*)(ws + 20971520);   // 8192 uint4 (128 KB)
  uint4* wfl  = (uint4*)(ws + 21004288);   // 8192 uint4 (128 KB)
  float* part = ws + 21037056;             // 1048576

  k_embed<<<4096, 256, 0, stream>>>(idx, (const float4*)table, (float4*)emb);
  // x_gates[32768,512] = emb[32768,128] @ W_ih[512,128]^T
  k_gemm_tn<<<dim3(512, 8, 1), 256, 0, stream>>>(emb, W_ih, xg, 128, 2, 512, 0);
  k_xln<<<8192, 256, 0, stream>>>((float4*)xg, (const float4*)g_ih,
                                  (const float4*)b_ih, (const float4*)b_hh);
  k_wprep<<<32, 256, 0, stream>>>(W_hh, wfh, wfl);
  k_scan<<<128, 512, 0, stream>>>(xg, wfh, wfl, h0, c0, g_hh, g_c, b_c, hsb);
  // partials[32][128,256] = hs[128,32768] @ W_out[256,32768]^T  (k-split 32)
  k_gemm_tn<<<dim3(2, 4, 32), 256, 0, stream>>>(hsb, W_out, part, 32768, 16, 256, 32768);
  k_reduce<<<128, 256, 0, stream>>>(part, b_out, out);
}